// Round 4
// baseline (653.774 us; speedup 1.0000x reference)
//
#include <hip/hip_runtime.h>
#include <cfloat>
#include <cmath>

#define V 128000
#define VQ (V / 4)
#define B 256
#define L 256
#define NB 21
#define CAPV 4096      // candidate capacity
#define CAPL 3840      // floor-selection bound (K==0 path)
#define NSMALL 1536    // O(n^2) exact paths below this; bisection above
static constexpr float EPSF = 1e-5f;

// ---------------- Threefry-2x32-20, JAX partitionable mode ----------------
__device__ __forceinline__ unsigned rotl32(unsigned x, int r) {
  return (x << r) | (x >> (32 - r));
}
__device__ __forceinline__ unsigned tf_bits(unsigned e) {
  const unsigned k0 = 0u, k1 = 42u;
  const unsigned k2 = k0 ^ k1 ^ 0x1BD11BDAu;
  unsigned x0 = 0u + k0;
  unsigned x1 = e + k1;
#define TF_RND(r) { x0 += x1; x1 = rotl32(x1, r); x1 ^= x0; }
  TF_RND(13) TF_RND(15) TF_RND(26) TF_RND(6)
  x0 += k1; x1 += k2 + 1u;
  TF_RND(17) TF_RND(29) TF_RND(16) TF_RND(24)
  x0 += k2; x1 += k0 + 2u;
  TF_RND(13) TF_RND(15) TF_RND(26) TF_RND(6)
  x0 += k0; x1 += k1 + 3u;
  TF_RND(17) TF_RND(29) TF_RND(16) TF_RND(24)
  x0 += k1; x1 += k2 + 4u;
  TF_RND(13) TF_RND(15) TF_RND(26) TF_RND(6)
  x0 += k2; x1 += k0 + 5u;
#undef TF_RND
  return x0 ^ x1;
}
__device__ __forceinline__ float gumbelf(unsigned e) {
  unsigned bits = tf_bits(e);
  float f = __uint_as_float((bits >> 9) | 0x3F800000u) - 1.0f;   // [0,1)
  float u = f + 1e-10f;      // (1.0f - 1e-10f) rounds to 1.0f -> no multiply
  u = fmaxf(u, 1e-10f);
  return -logf(-logf(u));
}

// order-preserving float->uint key
__device__ __forceinline__ unsigned flipkey(float v) {
  unsigned u = __float_as_uint(v);
  return (u & 0x80000000u) ? ~u : (u | 0x80000000u);
}
__device__ __forceinline__ float unflip(unsigned k) {
  return __uint_as_float((k & 0x80000000u) ? (k ^ 0x80000000u) : ~k);
}

// exact v for token idx: penalized override else raw/T (IEEE division)
__device__ __forceinline__ float probe_v(const int* hk, const float* hv,
                                         int idx, float raw, float T) {
  float v = raw / T;
  unsigned h = ((unsigned)idx * 2654435761u) >> 22;
  for (;;) {
    int k = hk[h];
    if (k == idx) { v = hv[h]; break; }
    if (k == -1) break;
    h = (h + 1) & 1023u;
  }
  return v;
}

// ---------------- LDS layout (dynamic, byte offsets) ----------------------
#define OFF_HREP 0         // 65536: [K==0] 2-replica hists; later sub/qraw scratch
#define OFF_LRAW 65536     // f32[4096] cand raw (also ids[256] early, hcntC overlay)
#define OFF_LI   81920     // i32[4096] cand idx (also hsumC overlay)
#define OFF_LV   98304     // f32[4096] cand v
#define OFF_LE   114688    // f32[4096] cand exp(v)
#define OFF_HK   131072    // i32[1024] hash keys (penalized ids)
#define OFF_HV   135168    // f32[1024] hash vals (penalized v)
#define OFF_STG  139264    // 128B reduce/scan staging
#define OFF_SCL  139392    // scalars
#define SMEM_SZ  139520

struct Scal {
  double A0;
  int pc, f0, f21, bstar, b2, nv, n2, qn, mode, floorV;
  float kth;
  int pad;
};

// ---------------- block reduce helpers ------------------------------------
__device__ __forceinline__ double bredd(double x, void* stg, int t) {
  double* s = (double*)stg;
  for (int o = 32; o; o >>= 1) x += __shfl_down(x, o, 64);
  if ((t & 63) == 0) s[t >> 6] = x;
  __syncthreads();
  if (t < 64) {
    double y = (t < 16) ? s[t] : 0.0;
    for (int o = 8; o; o >>= 1) y += __shfl_down(y, o, 64);
    if (t == 0) s[0] = y;
  }
  __syncthreads();
  double r = s[0];
  __syncthreads();
  return r;
}
__device__ __forceinline__ float bredminf(float x, void* stg, int t) {
  float* s = (float*)stg;
  for (int o = 32; o; o >>= 1) x = fminf(x, __shfl_down(x, o, 64));
  if ((t & 63) == 0) s[t >> 6] = x;
  __syncthreads();
  if (t < 64) {
    float y = (t < 16) ? s[t] : FLT_MAX;
    for (int o = 8; o; o >>= 1) y = fminf(y, __shfl_down(y, o, 64));
    if (t == 0) s[0] = y;
  }
  __syncthreads();
  float r = s[0];
  __syncthreads();
  return r;
}
__device__ __forceinline__ float bredmaxf(float x, void* stg, int t) {
  float* s = (float*)stg;
  for (int o = 32; o; o >>= 1) x = fmaxf(x, __shfl_down(x, o, 64));
  if ((t & 63) == 0) s[t >> 6] = x;
  __syncthreads();
  if (t < 64) {
    float y = (t < 16) ? s[t] : -FLT_MAX;
    for (int o = 8; o; o >>= 1) y = fmaxf(y, __shfl_down(y, o, 64));
    if (t == 0) s[0] = y;
  }
  __syncthreads();
  float r = s[0];
  __syncthreads();
  return r;
}
__device__ __forceinline__ void bredargmax(float v, int i, void* stg, int t,
                                           float& ov, int& oi) {
  float* sv = (float*)stg; int* si = (int*)stg + 16;
  for (int o = 32; o; o >>= 1) {
    float v2 = __shfl_down(v, o, 64); int i2 = __shfl_down(i, o, 64);
    if (v2 > v || (v2 == v && i2 < i)) { v = v2; i = i2; }
  }
  if ((t & 63) == 0) { sv[t >> 6] = v; si[t >> 6] = i; }
  __syncthreads();
  if (t < 64) {
    float y; int yi;
    if (t < 16) { y = sv[t]; yi = si[t]; } else { y = -FLT_MAX; yi = 0x7FFFFFFF; }
    for (int o = 8; o; o >>= 1) {
      float v2 = __shfl_down(y, o, 64); int i2 = __shfl_down(yi, o, 64);
      if (v2 > y || (v2 == y && i2 < yi)) { y = v2; yi = i2; }
    }
    if (t == 0) { sv[0] = y; si[0] = yi; }
  }
  __syncthreads();
  ov = sv[0]; oi = si[0];
  __syncthreads();
}

// wave-aggregated compaction: one atomic per qualifying wave-instruction
__device__ __forceinline__ void wave_push(bool pred, float val, int idx,
                                          int* counter, float* arrV, int* arrI,
                                          int lane) {
  unsigned long long m = __ballot(pred ? 1 : 0);
  int ccnt = __popcll(m);
  if (ccnt) {
    int leader = (int)__ffsll(m) - 1;
    int base = 0;
    if (lane == leader) base = atomicAdd(counter, ccnt);
    base = __shfl(base, leader, 64);
    if (pred) {
      int pos = base + __popcll(m & ((1ull << (unsigned)lane) - 1ull));
      if (pos < CAPV) { arrV[pos] = val; arrI[pos] = idx; }
    }
  }
}

// in-place descending inclusive prefix: arr[b] = sum_{b' >= b} arr[b']
template <typename T>
__device__ __forceinline__ void scan_desc(T* arr, int nbins, void* stg, int t) {
  T* s = (T*)stg;
  T carry = (T)0;
  for (int base = nbins - 1024; base >= 0; base -= 1024) {
    int bin = base + 1023 - t;
    T x = arr[bin];
    for (int o = 1; o < 64; o <<= 1) {
      T y = __shfl_up(x, o, 64);
      if ((t & 63) >= o) x += y;
    }
    if ((t & 63) == 63) s[t >> 6] = x;
    __syncthreads();
    if (t < 64) {
      T y = (t < 16) ? s[t] : (T)0;
      for (int o = 1; o < 16; o <<= 1) {
        T z = __shfl_up(y, o, 64);
        if (t >= o) y += z;
      }
      if (t < 16) s[t] = y;
    }
    __syncthreads();
    T add = (t >= 64) ? s[(t >> 6) - 1] : (T)0;
    arr[bin] = x + add + carry;
    carry = carry + s[15];
    __syncthreads();
  }
}

// ---------------- fused sampler -------------------------------------------
__global__ void __launch_bounds__(1024)
k_fused(const float* __restrict__ logits, const float* __restrict__ temp,
        const int* __restrict__ topk, const float* __restrict__ topp,
        const float* __restrict__ rep, const float* __restrict__ freq,
        const float* __restrict__ pres, const int* __restrict__ oids,
        float* __restrict__ out)
{
  extern __shared__ char smem[];
  unsigned* hcntR = (unsigned*)(smem + OFF_HREP);
  float*    hsumR = (float*)(smem + OFF_HREP + 32768);
  float*    lraw  = (float*)(smem + OFF_LRAW);
  int*      li    = (int*)(smem + OFF_LI);
  float*    lv    = (float*)(smem + OFF_LV);
  float*    le    = (float*)(smem + OFF_LE);
  int*      hk    = (int*)(smem + OFF_HK);
  float*    hv    = (float*)(smem + OFF_HV);
  void*     stg   = (void*)(smem + OFF_STG);
  Scal*     sc    = (Scal*)(smem + OFF_SCL);

  const int r = blockIdx.x, t = threadIdx.x;
  const int lane = t & 63;
  const float* row = logits + (size_t)r * V;
  const float Traw = temp[r];
  const float T = (Traw < EPSF) ? 1.0f : Traw;
  const int K = topk[r];
  const bool hasK = (K > 0);
  const int keff = hasK ? min(K, V) : V;
  const float tp = topp[r];
  const unsigned ebase = (unsigned)r * (unsigned)V;

  hk[t] = -1;
  if (t == 0) {
    sc->A0 = 0.0; sc->pc = 0; sc->f0 = -1; sc->f21 = 4095; sc->bstar = 4095;
    sc->b2 = -1; sc->nv = 0; sc->n2 = 0; sc->qn = 0; sc->mode = 0;
    sc->floorV = 0; sc->kth = -FLT_MAX;
  }
  if (!hasK) {
    for (int i = t; i < 8192; i += 1024) { hcntR[i] = 0u; hsumR[i] = 0.f; }
  }
  int* ids = (int*)lraw;                  // reuse candidate array early
  if (t < L) ids[t] = oids[r * L + t];
  __syncthreads();

  // ---- inline penalty: dedup output tokens, exact penalized v into hash
  if (t < L) {
    const int my = ids[t];
    int c = 0, firstpos = t;
    for (int j = 0; j < L; ++j) {
      int o = ids[j];
      if (o == my) { c++; if (j < firstpos) firstpos = j; }
    }
    if (firstpos == t) {                  // one writer per unique token
      float x = row[my];
      float rp = rep[r];
      x = (x > 0.f) ? (x / rp) : (x * rp);
      x = __fsub_rn(x, __fmul_rn((float)c, freq[r]));
      x = __fsub_rn(x, pres[r]);
      x = x / T;
      unsigned h = ((unsigned)my * 2654435761u) >> 22;
      while (atomicCAS(&hk[h], -1, my) != -1) h = (h + 1) & 1023u;
      hv[h] = x;
      atomicAdd(&sc->pc, 1);
    }
  }
  __syncthreads();
  const int pc = sc->pc;

  float lseF;
  int mode = 0, floorV = 0, n = 0, ntop = 0;
  double Sall = 0.0;

  if (hasK) {
    // ======== K>0: atomic-free stats pass + tau-based collect ========
    double dacc = 0.0;
    float mx = -FLT_MAX, s1 = 0.f, s2 = 0.f;
    for (int i4 = t; i4 < VQ; i4 += 1024) {
      const float4 x = reinterpret_cast<const float4*>(row)[i4];
      const float vs[4] = {x.x, x.y, x.z, x.w};
#pragma unroll
      for (int c = 0; c < 4; ++c) {
        float raw = vs[c];
        dacc += (double)expf(raw);
        mx = fmaxf(mx, raw);
        s1 += raw;
        s2 = fmaf(raw, raw, s2);
      }
    }
    lseF = (float)log(bredd(dacc, stg, t));
    const float M = bredmaxf(mx, stg, t);
    const double Sm = bredd((double)s1, stg, t);
    const double Sq = bredd((double)s2, stg, t);
    const float mu = (float)(Sm / (double)V);
    float var = (float)(Sq / (double)V) - mu * mu;
    float sig = sqrtf(fmaxf(var, 0.f));
    float step = (sig > 1e-6f) ? sig : 1.0f;
    const int NEED = keff + pc + 32;          // covers v-top-keff+ties & raw-top-21

    float tau = fminf(mu + 2.351f * sig, M);  // target count ~1200
    float tLo = 0.f, tHi = 0.f; int hasLo = 0, hasHi = 0;
    for (int it = 0; it < 40; ++it) {
      __syncthreads();
      if (t == 0) sc->nv = 0;
      __syncthreads();
      for (int i4 = t; i4 < VQ; i4 += 1024) {
        const float4 x = reinterpret_cast<const float4*>(row)[i4];
        const float vs[4] = {x.x, x.y, x.z, x.w};
#pragma unroll
        for (int c = 0; c < 4; ++c) {
          float raw = vs[c];
          wave_push(raw >= tau, raw, i4 * 4 + c, &sc->nv, lraw, li, lane);
        }
      }
      __syncthreads();
      int cnt = sc->nv;
      n = min(cnt, CAPV);
      if (cnt >= NEED && cnt <= CAPV) break;     // exact window verified
      if (cnt < NEED) { tHi = tau; hasHi = 1; }  // too few -> lower tau
      else           { tLo = tau; hasLo = 1; }   // too many -> raise tau
      if (hasLo && hasHi) {
        unsigned kl = flipkey(tLo), kh = flipkey(tHi);
        if (kh - kl < 2u) break;                 // adjacent keys: give up (ties)
        float ntau = unflip(kl + ((kh - kl) >> 1));
        if (ntau == tau) break;
        tau = ntau;
      } else if (cnt < NEED) tau = tau - step;
      else                   tau = tau + step;
    }
    ntop = n;
  } else {
    // ======== K==0 (~2% rows): exact v-domain histogram (low-contention) ====
    double dacc = 0.0, sacc = 0.0;
    for (int i4 = t; i4 < VQ; i4 += 1024) {
      const float4 x = reinterpret_cast<const float4*>(row)[i4];
      const float vs[4] = {x.x, x.y, x.z, x.w};
#pragma unroll
      for (int c = 0; c < 4; ++c) {
        float raw = vs[c];
        float v0 = raw / T;                       // bulk: unpenalized v (IEEE)
        unsigned bi = (((flipkey(v0)) >> 20) << 1) | (unsigned)(t & 1);
        atomicAdd(&hcntR[bi], 1u);
        float ev = expf(v0);
        atomicAdd(&hsumR[bi], ev);
        sacc += (double)ev;
        dacc += (double)expf(raw);
      }
    }
    __syncthreads();
    lseF = (float)log(bredd(dacc, stg, t));
    const double SallBulk = bredd(sacc, stg, t);
    // corrections: move <=256 penalized tokens to their exact v position
    double corr = 0.0;
    {
      int id = hk[t];
      if (id >= 0) {
        float raw = row[id];
        float v0 = raw / T;
        float vp = hv[t];
        unsigned b0 = ((flipkey(v0) >> 20) << 1);
        unsigned bp = ((flipkey(vp) >> 20) << 1);
        float e0 = expf(v0), ep = expf(vp);
        atomicSub(&hcntR[b0], 1u);
        atomicAdd(&hcntR[bp], 1u);
        atomicAdd(&hsumR[b0], -e0);
        atomicAdd(&hsumR[bp], ep);
        corr = (double)ep - (double)e0;
      }
    }
    Sall = SallBulk + bredd(corr, stg, t);
    // combine replicas into scan arrays (overlay on lraw/li)
    unsigned* hcntC = (unsigned*)lraw;
    float* hsumC = (float*)li;
    for (int b = t; b < 4096; b += 1024) {
      hcntC[b] = hcntR[2 * b] + hcntR[2 * b + 1];
      hsumC[b] = hsumR[2 * b] + hsumR[2 * b + 1];
    }
    __syncthreads();
    scan_desc<unsigned>(hcntC, 4096, stg, t);
    scan_desc<float>(hsumC, 4096, stg, t);
    // crossing-bin finds
    {
      const unsigned NEED2 = (unsigned)(21 + pc + 8);
      for (int b = t; b < 4096; b += 1024) {
        unsigned incl = hcntC[b]; unsigned abv = (b < 4095) ? hcntC[b + 1] : 0u;
        if (incl >= NEED2 && abv < NEED2) sc->f21 = b;
        unsigned below = (b > 0) ? hcntC[b - 1] : 0xFFFFFFFFu;
        if (incl <= (unsigned)CAPL && below > (unsigned)CAPL) sc->bstar = b;
      }
      const double PS0 = (double)tp * Sall;
      for (int b = t; b < 4096; b += 1024) {
        double incl = (double)hsumC[b];
        double abv = (b < 4095) ? (double)hsumC[b + 1] : 0.0;
        if (abv < PS0 && PS0 <= incl) sc->f0 = b;
      }
    }
    __syncthreads();
    if (t == 0) {
      int f0 = sc->f0;
      if (f0 < 0) { sc->mode = 2; sc->floorV = sc->bstar; }
      else {
        sc->A0 = (f0 < 4095) ? (double)hsumC[f0 + 1] : 0.0;
        int f21 = sc->f21;
        int fm = min(max(f0 - 1, 0), f21);
        int fb = min(f0, f21);
        if (hcntC[fm] <= (unsigned)CAPL) { sc->mode = 0; sc->floorV = fm; }
        else if (hcntC[fb] <= (unsigned)CAPL) { sc->mode = 0; sc->floorV = fb; }
        else { sc->mode = 1; sc->floorV = sc->bstar; }
      }
    }
    __syncthreads();
    mode = sc->mode;
    floorV = sc->floorV;
    // collect candidates by v-key (overwrites hcntC/hsumC = lraw/li)
    __syncthreads();
    if (t == 0) sc->nv = 0;
    __syncthreads();
    for (int i4 = t; i4 < VQ; i4 += 1024) {
      const float4 x = reinterpret_cast<const float4*>(row)[i4];
      const float vs[4] = {x.x, x.y, x.z, x.w};
#pragma unroll
      for (int c = 0; c < 4; ++c) {
        float raw = vs[c]; int idx = i4 * 4 + c;
        float v = probe_v(hk, hv, idx, raw, T);
        wave_push((int)(flipkey(v) >> 20) >= floorV, raw, idx,
                  &sc->nv, lraw, li, lane);
      }
    }
    __syncthreads();
    n = min(sc->nv, CAPV);
    // union in penalized tokens below floor (raw-top-20 exactness)
    {
      int id = hk[t];
      if (id >= 0) {
        float vpen = hv[t];
        if ((int)(flipkey(vpen) >> 20) < floorV) {
          float raw = row[id];
          int p = n + atomicAdd(&sc->n2, 1);
          if (p < CAPV) { lraw[p] = raw; li[p] = id; }
        }
      }
    }
    __syncthreads();
    ntop = min(n + sc->n2, CAPV);
  }

  // ---- candidate prep: exact v and exp(v)
  for (int j = t; j < n; j += 1024) {
    float v = probe_v(hk, hv, li[j], lraw[j], T);
    lv[j] = v; le[j] = expf(v);
  }
  __syncthreads();

  // ---- greedy argmax over candidates (contains the global v-max)
  float mg = -FLT_MAX; int mgi = 0x7FFFFFFF;
  for (int j = t; j < n; j += 1024) {
    float xj = lv[j]; int ij = li[j];
    if (xj > mg || (xj == mg && ij < mgi)) { mg = xj; mgi = ij; }
  }
  float gv; int gi;
  bredargmax(mg, mgi, stg, t, gv, gi);

  // ---- raw top-20 + logprob cols 1..20
  if (t < 20) {
    out[B + r * NB + 1 + t] = -INFINITY;
    out[B + B * NB + r * NB + 1 + t] = 0.f;
  }
  __syncthreads();
  if (ntop <= NSMALL) {
    for (int j = t; j < ntop; j += 1024) {
      float xj = lraw[j]; int ij = li[j];
      int rank = 0;
      for (int i = 0; i < ntop; ++i) {
        float xi = lraw[i]; int ii = li[i];
        rank += (xi > xj || (xi == xj && ii < ij)) ? 1 : 0;
      }
      if (rank < 20) {
        out[B + r * NB + 1 + rank] = xj - lseF;
        out[B + B * NB + r * NB + 1 + rank] = (float)ij;
      }
    }
  } else {
    // bisect the 21st raw key, then wave-parallel rank-count for qualifiers
    unsigned lo = 0u, hi = 0xFFFFFFFFu;
    while (lo < hi) {
      unsigned mid = lo + ((hi - lo) >> 1) + 1u;
      double part = 0.0;
      for (int j = t; j < ntop; j += 1024)
        part += (flipkey(lraw[j]) >= mid) ? 1.0 : 0.0;
      double cnt = bredd(part, stg, t);
      if (cnt >= 21.0) lo = mid; else hi = mid - 1u;
    }
    float* qraw = (float*)smem;                 // hrep region free now
    int* qidx = (int*)(smem + 256);
    for (int j = t; j < ntop; j += 1024)
      if (flipkey(lraw[j]) >= lo) {
        int p = atomicAdd(&sc->qn, 1);
        if (p < 64) { qraw[p] = lraw[j]; qidx[p] = li[j]; }
      }
    __syncthreads();
    const int qn = min(sc->qn, 64);
    const int w = t >> 6;
    for (int q = w; q < qn; q += 16) {
      float rq = qraw[q]; int iq = qidx[q];
      int cnt = 0;
      for (int i = lane; i < ntop; i += 64) {
        float xi = lraw[i]; int ii = li[i];
        cnt += (xi > rq || (xi == rq && ii < iq)) ? 1 : 0;
      }
      for (int o = 32; o; o >>= 1) cnt += __shfl_down(cnt, o, 64);
      if (lane == 0 && cnt < 20) {
        out[B + r * NB + 1 + cnt] = rq - lseF;
        out[B + B * NB + r * NB + 1 + cnt] = (float)iq;
      }
    }
  }
  __syncthreads();

  // ---- exact kth (K>0) and survivor mass S
  float kth = -FLT_MAX;
  double S;
  if (hasK) {
    if (n <= NSMALL) {
      for (int j = t; j < n; j += 1024) {
        float xj = lv[j];
        int g = 0, e = 0;
        for (int i = 0; i < n; ++i) { float xi = lv[i]; g += (xi > xj); e += (xi == xj); }
        if (g < keff && keff <= g + e) sc->kth = xj;
      }
      __syncthreads();
    } else {
      unsigned lo = 0u, hi = 0xFFFFFFFFu;
      while (lo < hi) {
        unsigned mid = lo + ((hi - lo) >> 1) + 1u;
        double part = 0.0;
        for (int j = t; j < n; j += 1024) part += (flipkey(lv[j]) >= mid) ? 1.0 : 0.0;
        double C = bredd(part, stg, t);
        if (C >= (double)keff) lo = mid; else hi = mid - 1u;
      }
      float cand = FLT_MAX;
      for (int j = t; j < n; j += 1024) if (flipkey(lv[j]) >= lo) cand = fminf(cand, lv[j]);
      float kk = bredminf(cand, stg, t);
      if (t == 0 && kk != FLT_MAX) sc->kth = kk;
      __syncthreads();
    }
    kth = sc->kth;
    double part = 0.0;
    for (int j = t; j < n; j += 1024) if (lv[j] >= kth) part += (double)le[j];
    S = bredd(part, stg, t);
  } else {
    S = Sall;
  }
  const double PS = (double)tp * S;

  // ---- top-p threshold: thr = min{x >= kth : sum_{w > x} e^w < PS}
  float thr;
  if (mode == 0) {
    if (n <= NSMALL) {
      float cand = FLT_MAX;
      for (int j = t; j < n; j += 1024) {
        float xj = lv[j];
        if (xj < kth) continue;
        double G = 0.0;
        for (int i = 0; i < n; ++i) { float xi = lv[i]; if (xi > xj) G += (double)le[i]; }
        if (G < PS) cand = fminf(cand, xj);
      }
      thr = bredminf(cand, stg, t);
      if (thr == FLT_MAX) thr = kth;
    } else {
      unsigned lo = hasK ? flipkey(kth) : ((unsigned)floorV << 20);
      unsigned hi = 0xFFFFFFFFu;
      while (lo < hi) {
        unsigned mid = lo + ((hi - lo) >> 1);
        double part = 0.0;
        for (int j = t; j < n; j += 1024)
          if (flipkey(lv[j]) > mid) part += (double)le[j];
        double G = bredd(part, stg, t);
        if (G < PS) hi = mid; else lo = mid + 1u;
      }
      float cand = FLT_MAX;
      for (int j = t; j < n; j += 1024) if (flipkey(lv[j]) >= lo) cand = fminf(cand, lv[j]);
      thr = bredminf(cand, stg, t);
      if (thr == FLT_MAX) thr = kth;
    }
  } else if (mode == 1) {
    // K==0 fat row: 12-bit sub-histogram of mass-crossing bin, exact inside
    const int bp0 = sc->f0;
    float* sub = (float*)smem;                    // hrep region scratch
    for (int i = t; i < 4096; i += 1024) sub[i] = 0.f;
    if (t == 0) sc->n2 = 0;
    __syncthreads();
    for (int i4 = t; i4 < VQ; i4 += 1024) {
      const float4 x = reinterpret_cast<const float4*>(row)[i4];
      const float vs[4] = {x.x, x.y, x.z, x.w};
#pragma unroll
      for (int c = 0; c < 4; ++c) {
        float raw = vs[c]; int idx = i4 * 4 + c;
        float v = probe_v(hk, hv, idx, raw, T);
        unsigned fk = flipkey(v);
        if ((int)(fk >> 20) == bp0) atomicAdd(&sub[(fk >> 8) & 0xFFFu], expf(v));
      }
    }
    __syncthreads();
    scan_desc<float>(sub, 4096, stg, t);
    const double A0 = sc->A0;
    for (int s2 = t; s2 < 4096; s2 += 1024) {
      double incl = A0 + (double)sub[s2];
      double abv = A0 + ((s2 < 4095) ? (double)sub[s2 + 1] : 0.0);
      if (abv < PS && PS <= incl) sc->b2 = s2;
    }
    __syncthreads();
    const int b2 = sc->b2;
    if (b2 < 0) {
      thr = unflip((unsigned)bp0 << 20);
    } else {
      const double A2 = A0 + ((b2 < 4095) ? (double)sub[b2 + 1] : 0.0);
      for (int i4 = t; i4 < VQ; i4 += 1024) {
        const float4 x = reinterpret_cast<const float4*>(row)[i4];
        const float vs[4] = {x.x, x.y, x.z, x.w};
#pragma unroll
        for (int c = 0; c < 4; ++c) {
          float raw = vs[c]; int idx = i4 * 4 + c;
          float v = probe_v(hk, hv, idx, raw, T);
          unsigned fk = flipkey(v);
          if ((int)(fk >> 20) == bp0 && (int)((fk >> 8) & 0xFFFu) == b2) {
            int p = atomicAdd(&sc->n2, 1);
            if (p < CAPV) { lv[p] = v; le[p] = expf(v); }
          }
        }
      }
      __syncthreads();
      const int n2 = min(sc->n2, CAPV);
      float cand = FLT_MAX;
      for (int j = t; j < n2; j += 1024) {
        float xj = lv[j];
        double G = A2;
        for (int i = 0; i < n2; ++i) { float xi = lv[i]; if (xi > xj) G += (double)le[i]; }
        if (G < PS) cand = fminf(cand, xj);
      }
      thr = bredminf(cand, stg, t);
      if (thr == FLT_MAX)
        thr = unflip(((unsigned)bp0 << 20) | ((unsigned)(b2 + 1) << 8));
    }
  } else {
    thr = -FLT_MAX;                               // mode 2: everything survives
  }

  // ---- gumbel argmax over survivors (v >= thr)
  float yv = -FLT_MAX; int yi = 0x7FFFFFFF;
  if (mode == 0) {
    for (int j = t; j < n; j += 1024) {
      float xj = lv[j];
      if (xj >= thr) {
        int ij = li[j];
        float y = xj + gumbelf(ebase + (unsigned)ij);
        if (y > yv || (y == yv && ij < yi)) { yv = y; yi = ij; }
      }
    }
  } else {
    for (int i4 = t; i4 < VQ; i4 += 1024) {       // rare K==0 fat rows
      const float4 x = reinterpret_cast<const float4*>(row)[i4];
      const float vs[4] = {x.x, x.y, x.z, x.w};
#pragma unroll
      for (int c = 0; c < 4; ++c) {
        float raw = vs[c]; int idx = i4 * 4 + c;
        float v = probe_v(hk, hv, idx, raw, T);
        if (v >= thr) {
          float y = v + gumbelf(ebase + (unsigned)idx);
          if (y > yv || (y == yv && idx < yi)) { yv = y; yi = idx; }
        }
      }
    }
  }
  float fy; int fyi;
  bredargmax(yv, yi, stg, t, fy, fyi);

  if (t == 0) {
    const int samp = (Traw < EPSF) ? gi : fyi;
    out[r] = (float)samp;                         // sampled_token_ids
    out[B + r * NB] = row[samp] - lseF;           // logprobs col 0
    out[B + B * NB + r * NB] = (float)samp;       // indices col 0
  }
}

// ---------------- launch ---------------------------------------------------
extern "C" void kernel_launch(void* const* d_in, const int* in_sizes, int n_in,
                              void* d_out, int out_size, void* d_ws, size_t ws_size,
                              hipStream_t stream) {
  const float* logits = (const float*)d_in[0];
  const float* temp   = (const float*)d_in[1];
  const int*   tkp    = (const int*)d_in[2];
  const float* tpp    = (const float*)d_in[3];
  const float* rep    = (const float*)d_in[4];
  const float* freq   = (const float*)d_in[5];
  const float* pres   = (const float*)d_in[6];
  const int*   oids   = (const int*)d_in[7];
  float* out = (float*)d_out;

  (void)hipFuncSetAttribute((const void*)k_fused,
                            hipFuncAttributeMaxDynamicSharedMemorySize, SMEM_SZ);

  k_fused<<<B, 1024, SMEM_SZ, stream>>>(logits, temp, tkp, tpp,
                                        rep, freq, pres, oids, out);
}

// Round 5
// 567.586 us; speedup vs baseline: 1.1519x; 1.1519x over previous
//
#include <hip/hip_runtime.h>
#include <cfloat>
#include <cmath>

#define V 128000
#define VQ (V / 4)
#define B 256
#define L 256
#define NB 21
#define CAPV 4096      // candidate capacity
#define CAPL 3840      // floor-selection bound (K==0 path)
static constexpr float EPSF = 1e-5f;

// ---------------- Threefry-2x32-20, JAX partitionable mode ----------------
__device__ __forceinline__ unsigned rotl32(unsigned x, int r) {
  return (x << r) | (x >> (32 - r));
}
__device__ __forceinline__ unsigned tf_bits(unsigned e) {
  const unsigned k0 = 0u, k1 = 42u;
  const unsigned k2 = k0 ^ k1 ^ 0x1BD11BDAu;
  unsigned x0 = 0u + k0;
  unsigned x1 = e + k1;
#define TF_RND(r) { x0 += x1; x1 = rotl32(x1, r); x1 ^= x0; }
  TF_RND(13) TF_RND(15) TF_RND(26) TF_RND(6)
  x0 += k1; x1 += k2 + 1u;
  TF_RND(17) TF_RND(29) TF_RND(16) TF_RND(24)
  x0 += k2; x1 += k0 + 2u;
  TF_RND(13) TF_RND(15) TF_RND(26) TF_RND(6)
  x0 += k0; x1 += k1 + 3u;
  TF_RND(17) TF_RND(29) TF_RND(16) TF_RND(24)
  x0 += k1; x1 += k2 + 4u;
  TF_RND(13) TF_RND(15) TF_RND(26) TF_RND(6)
  x0 += k2; x1 += k0 + 5u;
#undef TF_RND
  return x0 ^ x1;
}
__device__ __forceinline__ float gumbelf(unsigned e) {
  unsigned bits = tf_bits(e);
  float f = __uint_as_float((bits >> 9) | 0x3F800000u) - 1.0f;   // [0,1)
  float u = f + 1e-10f;      // (1.0f - 1e-10f) rounds to 1.0f -> no multiply
  u = fmaxf(u, 1e-10f);
  return -logf(-logf(u));
}

// order-preserving float->uint key
__device__ __forceinline__ unsigned flipkey(float v) {
  unsigned u = __float_as_uint(v);
  return (u & 0x80000000u) ? ~u : (u | 0x80000000u);
}
__device__ __forceinline__ float unflip(unsigned k) {
  return __uint_as_float((k & 0x80000000u) ? (k ^ 0x80000000u) : ~k);
}

// exact v for token idx: penalized override else raw/T (IEEE division)
__device__ __forceinline__ float probe_v(const int* hk, const float* hv,
                                         int idx, float raw, float T) {
  float v = raw / T;
  unsigned h = ((unsigned)idx * 2654435761u) >> 22;
  for (;;) {
    int k = hk[h];
    if (k == idx) { v = hv[h]; break; }
    if (k == -1) break;
    h = (h + 1) & 1023u;
  }
  return v;
}

// ---------------- LDS layout (dynamic, byte offsets) ----------------------
#define OFF_LRAW 0         // f32[4096] cand raw (ids[256] early; hcntC overlay)
#define OFF_LI   16384     // i32[4096] cand idx (hsumC overlay; mode1 e scratch)
#define OFF_PK   32768     // u64[4096] sort keys | u32[8192] hcntR (K==0 pass A)
#define OFF_EXCL 65536     // f64[4096] excl prefix | f32[8192] hsumR | f32 sub
#define OFF_HK   98304     // i32[1024] hash keys (penalized ids)
#define OFF_HV   102400    // f32[1024] hash vals (penalized v)
#define OFF_STG  106496    // 128B reduce/scan staging
#define OFF_SCL  106624    // scalars
#define SMEM_SZ  106752

struct Scal {
  double A0, tot;
  int pc, f0, f21, bstar, b2, nv, n2, mode, floorV, pad;
};

// ---------------- block reduce helpers ------------------------------------
__device__ __forceinline__ double bredd(double x, void* stg, int t) {
  double* s = (double*)stg;
  for (int o = 32; o; o >>= 1) x += __shfl_down(x, o, 64);
  if ((t & 63) == 0) s[t >> 6] = x;
  __syncthreads();
  if (t < 64) {
    double y = (t < 16) ? s[t] : 0.0;
    for (int o = 8; o; o >>= 1) y += __shfl_down(y, o, 64);
    if (t == 0) s[0] = y;
  }
  __syncthreads();
  double r = s[0];
  __syncthreads();
  return r;
}
__device__ __forceinline__ float bredminf(float x, void* stg, int t) {
  float* s = (float*)stg;
  for (int o = 32; o; o >>= 1) x = fminf(x, __shfl_down(x, o, 64));
  if ((t & 63) == 0) s[t >> 6] = x;
  __syncthreads();
  if (t < 64) {
    float y = (t < 16) ? s[t] : FLT_MAX;
    for (int o = 8; o; o >>= 1) y = fminf(y, __shfl_down(y, o, 64));
    if (t == 0) s[0] = y;
  }
  __syncthreads();
  float r = s[0];
  __syncthreads();
  return r;
}
__device__ __forceinline__ float bredmaxf(float x, void* stg, int t) {
  float* s = (float*)stg;
  for (int o = 32; o; o >>= 1) x = fmaxf(x, __shfl_down(x, o, 64));
  if ((t & 63) == 0) s[t >> 6] = x;
  __syncthreads();
  if (t < 64) {
    float y = (t < 16) ? s[t] : -FLT_MAX;
    for (int o = 8; o; o >>= 1) y = fmaxf(y, __shfl_down(y, o, 64));
    if (t == 0) s[0] = y;
  }
  __syncthreads();
  float r = s[0];
  __syncthreads();
  return r;
}
__device__ __forceinline__ void bredargmax(float v, int i, void* stg, int t,
                                           float& ov, int& oi) {
  float* sv = (float*)stg; int* si = (int*)stg + 16;
  for (int o = 32; o; o >>= 1) {
    float v2 = __shfl_down(v, o, 64); int i2 = __shfl_down(i, o, 64);
    if (v2 > v || (v2 == v && i2 < i)) { v = v2; i = i2; }
  }
  if ((t & 63) == 0) { sv[t >> 6] = v; si[t >> 6] = i; }
  __syncthreads();
  if (t < 64) {
    float y; int yi;
    if (t < 16) { y = sv[t]; yi = si[t]; } else { y = -FLT_MAX; yi = 0x7FFFFFFF; }
    for (int o = 8; o; o >>= 1) {
      float v2 = __shfl_down(y, o, 64); int i2 = __shfl_down(yi, o, 64);
      if (v2 > y || (v2 == y && i2 < yi)) { y = v2; yi = i2; }
    }
    if (t == 0) { sv[0] = y; si[0] = yi; }
  }
  __syncthreads();
  ov = sv[0]; oi = si[0];
  __syncthreads();
}

// wave-aggregated compaction: one atomic per qualifying wave-instruction
__device__ __forceinline__ void wave_push(bool pred, float val, int idx,
                                          int* counter, float* arrV, int* arrI,
                                          int lane) {
  unsigned long long m = __ballot(pred ? 1 : 0);
  int ccnt = __popcll(m);
  if (ccnt) {
    int leader = (int)__ffsll(m) - 1;
    int base = 0;
    if (lane == leader) base = atomicAdd(counter, ccnt);
    base = __shfl(base, leader, 64);
    if (pred) {
      int pos = base + __popcll(m & ((1ull << (unsigned)lane) - 1ull));
      if (pos < CAPV) { arrV[pos] = val; arrI[pos] = idx; }
    }
  }
}

// in-place descending inclusive prefix: arr[b] = sum_{b' >= b} arr[b']
template <typename T>
__device__ __forceinline__ void scan_desc(T* arr, int nbins, void* stg, int t) {
  T* s = (T*)stg;
  T carry = (T)0;
  for (int base = nbins - 1024; base >= 0; base -= 1024) {
    int bin = base + 1023 - t;
    T x = arr[bin];
    for (int o = 1; o < 64; o <<= 1) {
      T y = __shfl_up(x, o, 64);
      if ((t & 63) >= o) x += y;
    }
    if ((t & 63) == 63) s[t >> 6] = x;
    __syncthreads();
    if (t < 64) {
      T y = (t < 16) ? s[t] : (T)0;
      for (int o = 1; o < 16; o <<= 1) {
        T z = __shfl_up(y, o, 64);
        if (t >= o) y += z;
      }
      if (t < 16) s[t] = y;
    }
    __syncthreads();
    T add = (t >= 64) ? s[(t >> 6) - 1] : (T)0;
    arr[bin] = x + add + carry;
    carry = carry + s[15];
    __syncthreads();
  }
}

// descending bitonic sort of u64 keys in LDS (N2 = power of 2)
__device__ __forceinline__ void bitonic_desc(unsigned long long* pk, int N2, int t) {
  for (unsigned k = 2; k <= (unsigned)N2; k <<= 1) {
    for (unsigned s = k >> 1; s > 0; s >>= 1) {
      __syncthreads();
      for (int i = t; i < N2; i += 1024) {
        int j = i ^ (int)s;
        if (j > i) {
          unsigned long long a = pk[i], b = pk[j];
          bool up = ((i & (int)k) == 0);
          if (up ? (a < b) : (a > b)) { pk[i] = b; pk[j] = a; }
        }
      }
    }
  }
  __syncthreads();
}
__device__ __forceinline__ int npow2(int m) {
  int N2 = 1;
  while (N2 < m) N2 <<= 1;
  return N2;
}

// ---------------- fused sampler -------------------------------------------
__global__ void __launch_bounds__(1024)
k_fused(const float* __restrict__ logits, const float* __restrict__ temp,
        const int* __restrict__ topk, const float* __restrict__ topp,
        const float* __restrict__ rep, const float* __restrict__ freq,
        const float* __restrict__ pres, const int* __restrict__ oids,
        float* __restrict__ out)
{
  extern __shared__ char smem[];
  float*              lraw = (float*)(smem + OFF_LRAW);
  int*                li   = (int*)(smem + OFF_LI);
  unsigned long long* pk   = (unsigned long long*)(smem + OFF_PK);
  double*             excl = (double*)(smem + OFF_EXCL);
  unsigned*           hcntR = (unsigned*)(smem + OFF_PK);    // K==0 pass A
  float*              hsumR = (float*)(smem + OFF_EXCL);     // K==0 pass A
  int*                hk   = (int*)(smem + OFF_HK);
  float*              hv   = (float*)(smem + OFF_HV);
  void*               stg  = (void*)(smem + OFF_STG);
  Scal*               sc   = (Scal*)(smem + OFF_SCL);

  const int r = blockIdx.x, t = threadIdx.x;
  const int lane = t & 63;
  const float* row = logits + (size_t)r * V;
  const float Traw = temp[r];
  const float T = (Traw < EPSF) ? 1.0f : Traw;
  const int K = topk[r];
  const bool hasK = (K > 0);
  const int keff = hasK ? min(K, V) : V;
  const float tp = topp[r];
  const unsigned ebase = (unsigned)r * (unsigned)V;

  hk[t] = -1;
  if (t == 0) {
    sc->A0 = 0.0; sc->tot = 0.0; sc->pc = 0; sc->f0 = -1; sc->f21 = 4095;
    sc->bstar = 4095; sc->b2 = -1; sc->nv = 0; sc->n2 = 0;
    sc->mode = 0; sc->floorV = 0;
  }
  if (!hasK) {
    for (int i = t; i < 8192; i += 1024) { hcntR[i] = 0u; hsumR[i] = 0.f; }
  }
  int* ids = (int*)lraw;                  // reuse candidate array early
  if (t < L) ids[t] = oids[r * L + t];
  __syncthreads();

  // ---- inline penalty: dedup output tokens, exact penalized v into hash
  if (t < L) {
    const int my = ids[t];
    int c = 0, firstpos = t;
    for (int j = 0; j < L; ++j) {
      int o = ids[j];
      if (o == my) { c++; if (j < firstpos) firstpos = j; }
    }
    if (firstpos == t) {                  // one writer per unique token
      float x = row[my];
      float rp = rep[r];
      x = (x > 0.f) ? (x / rp) : (x * rp);
      x = __fsub_rn(x, __fmul_rn((float)c, freq[r]));
      x = __fsub_rn(x, pres[r]);
      x = x / T;
      unsigned h = ((unsigned)my * 2654435761u) >> 22;
      while (atomicCAS(&hk[h], -1, my) != -1) h = (h + 1) & 1023u;
      hv[h] = x;
      atomicAdd(&sc->pc, 1);
    }
  }
  __syncthreads();
  const int pc = sc->pc;

  float lseF;
  int mode = 0, floorV = 0, n = 0, ntop = 0;
  double Sall = 0.0;

  if (hasK) {
    // ======== K>0: atomic-free stats pass + tau-based collect ========
    double dacc = 0.0;
    float mx = -FLT_MAX, s1 = 0.f, s2 = 0.f;
    for (int i4 = t; i4 < VQ; i4 += 1024) {
      const float4 x = reinterpret_cast<const float4*>(row)[i4];
      const float vs[4] = {x.x, x.y, x.z, x.w};
#pragma unroll
      for (int c = 0; c < 4; ++c) {
        float raw = vs[c];
        dacc += (double)expf(raw);
        mx = fmaxf(mx, raw);
        s1 += raw;
        s2 = fmaf(raw, raw, s2);
      }
    }
    lseF = (float)log(bredd(dacc, stg, t));
    const float M = bredmaxf(mx, stg, t);
    const double Sm = bredd((double)s1, stg, t);
    const double Sq = bredd((double)s2, stg, t);
    const float mu = (float)(Sm / (double)V);
    float var = (float)(Sq / (double)V) - mu * mu;
    float sig = sqrtf(fmaxf(var, 0.f));
    float step = (sig > 1e-6f) ? sig : 1.0f;
    const int NEED = keff + pc + 32;          // covers v-top-keff+ties & raw-top-21

    float tau = fminf(mu + 2.575f * sig, M);  // target count ~600
    float tLo = 0.f, tHi = 0.f; int hasLo = 0, hasHi = 0;
    for (int it = 0; it < 40; ++it) {
      __syncthreads();
      if (t == 0) sc->nv = 0;
      __syncthreads();
      for (int i4 = t; i4 < VQ; i4 += 1024) {
        const float4 x = reinterpret_cast<const float4*>(row)[i4];
        const float vs[4] = {x.x, x.y, x.z, x.w};
#pragma unroll
        for (int c = 0; c < 4; ++c) {
          float raw = vs[c];
          wave_push(raw >= tau, raw, i4 * 4 + c, &sc->nv, lraw, li, lane);
        }
      }
      __syncthreads();
      int cnt = sc->nv;
      n = min(cnt, CAPV);
      if (cnt >= NEED && cnt <= CAPV) break;     // exact window verified
      if (cnt < NEED) { tHi = tau; hasHi = 1; }  // too few -> lower tau
      else           { tLo = tau; hasLo = 1; }   // too many -> raise tau
      if (hasLo && hasHi) {
        unsigned kl = flipkey(tLo), kh = flipkey(tHi);
        if (kh - kl < 2u) break;                 // adjacent keys: give up (ties)
        float ntau = unflip(kl + ((kh - kl) >> 1));
        if (ntau == tau) break;
        tau = ntau;
      } else if (cnt < NEED) tau = tau - step;
      else                   tau = tau + step;
    }
    ntop = n;
  } else {
    // ======== K==0 (~2% rows): exact v-domain histogram (2 replicas) ====
    double dacc = 0.0, sacc = 0.0;
    for (int i4 = t; i4 < VQ; i4 += 1024) {
      const float4 x = reinterpret_cast<const float4*>(row)[i4];
      const float vs[4] = {x.x, x.y, x.z, x.w};
#pragma unroll
      for (int c = 0; c < 4; ++c) {
        float raw = vs[c];
        float v0 = raw / T;                       // bulk: unpenalized v (IEEE)
        unsigned bi = (((flipkey(v0)) >> 20) << 1) | (unsigned)(t & 1);
        atomicAdd(&hcntR[bi], 1u);
        float ev = expf(v0);
        atomicAdd(&hsumR[bi], ev);
        sacc += (double)ev;
        dacc += (double)expf(raw);
      }
    }
    __syncthreads();
    lseF = (float)log(bredd(dacc, stg, t));
    const double SallBulk = bredd(sacc, stg, t);
    // corrections: move <=256 penalized tokens to their exact v position
    double corr = 0.0;
    {
      int id = hk[t];
      if (id >= 0) {
        float raw = row[id];
        float v0 = raw / T;
        float vp = hv[t];
        unsigned b0 = ((flipkey(v0) >> 20) << 1);
        unsigned bp = ((flipkey(vp) >> 20) << 1);
        float e0 = expf(v0), ep = expf(vp);
        atomicSub(&hcntR[b0], 1u);
        atomicAdd(&hcntR[bp], 1u);
        atomicAdd(&hsumR[b0], -e0);
        atomicAdd(&hsumR[bp], ep);
        corr = (double)ep - (double)e0;
      }
    }
    Sall = SallBulk + bredd(corr, stg, t);
    // combine replicas into scan arrays (overlay on lraw/li)
    unsigned* hcntC = (unsigned*)lraw;
    float* hsumC = (float*)li;
    for (int b = t; b < 4096; b += 1024) {
      hcntC[b] = hcntR[2 * b] + hcntR[2 * b + 1];
      hsumC[b] = hsumR[2 * b] + hsumR[2 * b + 1];
    }
    __syncthreads();
    scan_desc<unsigned>(hcntC, 4096, stg, t);
    scan_desc<float>(hsumC, 4096, stg, t);
    // crossing-bin finds
    {
      const unsigned NEED2 = (unsigned)(21 + pc + 8);
      for (int b = t; b < 4096; b += 1024) {
        unsigned incl = hcntC[b]; unsigned abv = (b < 4095) ? hcntC[b + 1] : 0u;
        if (incl >= NEED2 && abv < NEED2) sc->f21 = b;
        unsigned below = (b > 0) ? hcntC[b - 1] : 0xFFFFFFFFu;
        if (incl <= (unsigned)CAPL && below > (unsigned)CAPL) sc->bstar = b;
      }
      const double PS0 = (double)tp * Sall;
      for (int b = t; b < 4096; b += 1024) {
        double incl = (double)hsumC[b];
        double abv = (b < 4095) ? (double)hsumC[b + 1] : 0.0;
        if (abv < PS0 && PS0 <= incl) sc->f0 = b;
      }
    }
    __syncthreads();
    if (t == 0) {
      int f0 = sc->f0;
      if (f0 < 0) { sc->mode = 2; sc->floorV = sc->bstar; }
      else {
        sc->A0 = (f0 < 4095) ? (double)hsumC[f0 + 1] : 0.0;
        int f21 = sc->f21;
        int fm = min(max(f0 - 1, 0), f21);
        int fb = min(f0, f21);
        if (hcntC[fm] <= (unsigned)CAPL) { sc->mode = 0; sc->floorV = fm; }
        else if (hcntC[fb] <= (unsigned)CAPL) { sc->mode = 0; sc->floorV = fb; }
        else { sc->mode = 1; sc->floorV = sc->bstar; }
      }
    }
    __syncthreads();
    mode = sc->mode;
    floorV = sc->floorV;
    // collect candidates by v-key (overwrites hcntC/hsumC = lraw/li)
    __syncthreads();
    if (t == 0) sc->nv = 0;
    __syncthreads();
    for (int i4 = t; i4 < VQ; i4 += 1024) {
      const float4 x = reinterpret_cast<const float4*>(row)[i4];
      const float vs[4] = {x.x, x.y, x.z, x.w};
#pragma unroll
      for (int c = 0; c < 4; ++c) {
        float raw = vs[c]; int idx = i4 * 4 + c;
        float v = probe_v(hk, hv, idx, raw, T);
        wave_push((int)(flipkey(v) >> 20) >= floorV, raw, idx,
                  &sc->nv, lraw, li, lane);
      }
    }
    __syncthreads();
    n = min(sc->nv, CAPV);
    // union in penalized tokens below floor (raw-top-20 exactness)
    {
      int id = hk[t];
      if (id >= 0) {
        float vpen = hv[t];
        if ((int)(flipkey(vpen) >> 20) < floorV) {
          float raw = row[id];
          int p = n + atomicAdd(&sc->n2, 1);
          if (p < CAPV) { lraw[p] = raw; li[p] = id; }
        }
      }
    }
    __syncthreads();
    ntop = min(n + sc->n2, CAPV);
  }

  // ---- safety pad for top-20 outputs
  if (t < 20) {
    out[B + r * NB + 1 + t] = -INFINITY;
    out[B + B * NB + r * NB + 1 + t] = 0.f;
  }

  // ---- sort #2: raw keys desc -> top-20 + logprob cols 1..20
  {
    const int N2r = npow2(max(ntop, 2));
    for (int i = t; i < N2r; i += 1024) pk[i] = 0ull;
    __syncthreads();
    for (int j = t; j < ntop; j += 1024)
      pk[j] = ((unsigned long long)flipkey(lraw[j]) << 32) |
              (unsigned long long)(unsigned)(~li[j]);
    __syncthreads();
    bitonic_desc(pk, N2r, t);
    if (t < 20 && t < ntop) {
      unsigned long long p = pk[t];
      float rawv = unflip((unsigned)(p >> 32));
      int idx = (int)(~(unsigned)(p & 0xFFFFFFFFu));
      out[B + r * NB + 1 + t] = rawv - lseF;
      out[B + B * NB + r * NB + 1 + t] = (float)idx;
    }
    __syncthreads();
  }

  // ---- sort #1: v keys desc over n main candidates
  {
    const int N2v = npow2(max(n, 2));
    for (int i = t; i < N2v; i += 1024) pk[i] = 0ull;
    __syncthreads();
    for (int j = t; j < n; j += 1024) {
      float v = probe_v(hk, hv, li[j], lraw[j], T);
      pk[j] = ((unsigned long long)flipkey(v) << 32) |
              (unsigned long long)(unsigned)(~li[j]);
    }
    __syncthreads();
    bitonic_desc(pk, N2v, t);
  }
  const int gi = (n > 0) ? (int)(~(unsigned)(pk[0] & 0xFFFFFFFFu)) : 0;

  // ---- deterministic double prefix of exp(v) in sorted-desc order
  {
    const int wid = t >> 6;
    double e0 = 0, e1 = 0, e2 = 0, e3 = 0;
    const int j0 = t * 4;
    if (j0 + 0 < n) e0 = (double)expf(unflip((unsigned)(pk[j0 + 0] >> 32)));
    if (j0 + 1 < n) e1 = (double)expf(unflip((unsigned)(pk[j0 + 1] >> 32)));
    if (j0 + 2 < n) e2 = (double)expf(unflip((unsigned)(pk[j0 + 2] >> 32)));
    if (j0 + 3 < n) e3 = (double)expf(unflip((unsigned)(pk[j0 + 3] >> 32)));
    const double ts = e0 + e1 + e2 + e3;
    double x = ts;
    for (int o = 1; o < 64; o <<= 1) {
      double y = __shfl_up(x, o, 64);
      if (lane >= o) x += y;
    }
    if (lane == 63) ((double*)stg)[wid] = x;   // wave totals
    __syncthreads();
    if (t < 64) {
      double y = (t < 16) ? ((double*)stg)[t] : 0.0;
      double z = y;
      for (int o = 1; o < 16; o <<= 1) {
        double w = __shfl_up(z, o, 64);
        if (t >= o) z += w;
      }
      if (t < 16) ((double*)stg)[t] = z - y;   // exclusive wave base
      if (t == 15) sc->tot = z;                // grand total
    }
    __syncthreads();
    double base = ((double*)stg)[wid] + (x - ts);
    if (j0 + 0 < n) excl[j0 + 0] = base;
    base += e0;
    if (j0 + 1 < n) excl[j0 + 1] = base;
    base += e1;
    if (j0 + 2 < n) excl[j0 + 2] = base;
    base += e2;
    if (j0 + 3 < n) excl[j0 + 3] = base;
    __syncthreads();
  }

  // ---- S (survivor mass) and search limit
  double S;
  int limit;
  if (hasK) {
    const int m0 = min(keff, n) - 1;
    const unsigned kthkey = (unsigned)(pk[m0] >> 32);
    double cp = 0.0;
    for (int j = t; j < n; j += 1024)
      cp += ((unsigned)(pk[j] >> 32) >= kthkey) ? 1.0 : 0.0;
    const int mEnd = (int)(bredd(cp, stg, t) + 0.5);
    limit = mEnd;
    S = (mEnd < n) ? excl[mEnd] : sc->tot;
  } else {
    limit = n;
    S = Sall;
  }
  const double PS = (double)tp * S;

  // ---- top-p threshold
  float thr;
  if (mode == 0) {
    float bj = -1.0f;
    for (int j = t; j < limit; j += 1024)
      if (excl[j] < PS) bj = fmaxf(bj, (float)j);
    const float fj = bredmaxf(bj, stg, t);
    const int jstar = (int)fj;
    thr = (jstar >= 0) ? unflip((unsigned)(pk[jstar] >> 32))
                       : unflip((unsigned)(pk[0] >> 32));
  } else if (mode == 1) {
    // K==0 fat row: 12-bit sub-histogram of mass-crossing bin, exact inside
    const int bp0 = sc->f0;
    float* sub = (float*)excl;                    // excl dead in mode 1
    for (int i = t; i < 4096; i += 1024) sub[i] = 0.f;
    if (t == 0) sc->n2 = 0;
    __syncthreads();
    for (int i4 = t; i4 < VQ; i4 += 1024) {
      const float4 x = reinterpret_cast<const float4*>(row)[i4];
      const float vs[4] = {x.x, x.y, x.z, x.w};
#pragma unroll
      for (int c = 0; c < 4; ++c) {
        float raw = vs[c]; int idx = i4 * 4 + c;
        float v = probe_v(hk, hv, idx, raw, T);
        unsigned fk = flipkey(v);
        if ((int)(fk >> 20) == bp0) atomicAdd(&sub[(fk >> 8) & 0xFFFu], expf(v));
      }
    }
    __syncthreads();
    scan_desc<float>(sub, 4096, stg, t);
    const double A0 = sc->A0;
    for (int s2 = t; s2 < 4096; s2 += 1024) {
      double incl = A0 + (double)sub[s2];
      double abv = A0 + ((s2 < 4095) ? (double)sub[s2 + 1] : 0.0);
      if (abv < PS && PS <= incl) sc->b2 = s2;
    }
    __syncthreads();
    const int b2 = sc->b2;
    if (b2 < 0) {
      thr = unflip((unsigned)bp0 << 20);
    } else {
      const double A2 = A0 + ((b2 < 4095) ? (double)sub[b2 + 1] : 0.0);
      float* mv = lraw;                           // member v (lraw scratch)
      float* me = (float*)li;                     // member exp (li scratch)
      for (int i4 = t; i4 < VQ; i4 += 1024) {
        const float4 x = reinterpret_cast<const float4*>(row)[i4];
        const float vs[4] = {x.x, x.y, x.z, x.w};
#pragma unroll
        for (int c = 0; c < 4; ++c) {
          float raw = vs[c]; int idx = i4 * 4 + c;
          float v = probe_v(hk, hv, idx, raw, T);
          unsigned fk = flipkey(v);
          if ((int)(fk >> 20) == bp0 && (int)((fk >> 8) & 0xFFFu) == b2) {
            int p = atomicAdd(&sc->n2, 1);
            if (p < CAPV) { mv[p] = v; me[p] = expf(v); }
          }
        }
      }
      __syncthreads();
      const int n2 = min(sc->n2, CAPV);
      float cand = FLT_MAX;
      for (int j = t; j < n2; j += 1024) {
        float xj = mv[j];
        double G = A2;
        for (int i = 0; i < n2; ++i) { float xi = mv[i]; if (xi > xj) G += (double)me[i]; }
        if (G < PS) cand = fminf(cand, xj);
      }
      thr = bredminf(cand, stg, t);
      if (thr == FLT_MAX)
        thr = unflip(((unsigned)bp0 << 20) | ((unsigned)(b2 + 1) << 8));
    }
  } else {
    thr = -FLT_MAX;                               // mode 2: everything survives
  }

  // ---- gumbel argmax over survivors (v >= thr)
  float yv = -FLT_MAX; int yi = 0x7FFFFFFF;
  if (mode == 0) {
    for (int j = t; j < limit; j += 1024) {
      unsigned long long p = pk[j];
      float v = unflip((unsigned)(p >> 32));
      if (v >= thr) {
        int ij = (int)(~(unsigned)(p & 0xFFFFFFFFu));
        float y = v + gumbelf(ebase + (unsigned)ij);
        if (y > yv || (y == yv && ij < yi)) { yv = y; yi = ij; }
      }
    }
  } else {
    for (int i4 = t; i4 < VQ; i4 += 1024) {       // rare K==0 fat rows
      const float4 x = reinterpret_cast<const float4*>(row)[i4];
      const float vs[4] = {x.x, x.y, x.z, x.w};
#pragma unroll
      for (int c = 0; c < 4; ++c) {
        float raw = vs[c]; int idx = i4 * 4 + c;
        float v = probe_v(hk, hv, idx, raw, T);
        if (v >= thr) {
          float y = v + gumbelf(ebase + (unsigned)idx);
          if (y > yv || (y == yv && idx < yi)) { yv = y; yi = idx; }
        }
      }
    }
  }
  float fy; int fyi;
  bredargmax(yv, yi, stg, t, fy, fyi);

  if (t == 0) {
    const int samp = (Traw < EPSF) ? gi : fyi;
    out[r] = (float)samp;                         // sampled_token_ids
    out[B + r * NB] = row[samp] - lseF;           // logprobs col 0
    out[B + B * NB + r * NB] = (float)samp;       // indices col 0
  }
}

// ---------------- launch ---------------------------------------------------
extern "C" void kernel_launch(void* const* d_in, const int* in_sizes, int n_in,
                              void* d_out, int out_size, void* d_ws, size_t ws_size,
                              hipStream_t stream) {
  const float* logits = (const float*)d_in[0];
  const float* temp   = (const float*)d_in[1];
  const int*   tkp    = (const int*)d_in[2];
  const float* tpp    = (const float*)d_in[3];
  const float* rep    = (const float*)d_in[4];
  const float* freq   = (const float*)d_in[5];
  const float* pres   = (const float*)d_in[6];
  const int*   oids   = (const int*)d_in[7];
  float* out = (float*)d_out;

  (void)hipFuncSetAttribute((const void*)k_fused,
                            hipFuncAttributeMaxDynamicSharedMemorySize, SMEM_SZ);

  k_fused<<<B, 1024, SMEM_SZ, stream>>>(logits, temp, tkp, tpp,
                                        rep, freq, pres, oids, out);
}